// Round 11
// baseline (273.759 us; speedup 1.0000x reference)
//
#include <hip/hip_runtime.h>

// GCN: N=100000, E=800000, D=128, two GraphConv layers.
// R15 = R14 (best: 264.3us) + wave-tile fused gather+GEMM, fixing R9's
// three fusion mistakes:
//  - ONE gather pass per block (16 nodes x 16 lanes = identical granularity
//    and inner loop to the standalone gather; R9 had 4 serial passes)
//  - barrier over 16 nodes only (R9: 64)
//  - no W LDS staging (4.4KB A-tile only -> gather-optimal occupancy);
//    B-frags from global wb (32KB, L1-resident). R10 showed global-B is bad
//    when it carries the whole GEMM; here it is a small tail phase hidden
//    by other blocks' gather waves. All 4 waves do MFMA (32 cols each).
// Saves the agg round-trip (102MB across both layers) + 2 launches.
// Numerics bit-identical to R14 (same gather order, same rounding points).
// hs of layer 1 goes to the old agg region (fused kernel cannot write its
// own gather source); layer 2 gathers from there and writes fp32 out.

#define NN 100000
#define EE 800000
#define DD 128
#define NB1 98            // ceil(NN / 1024) blocks for scan level 1
#define NTILE (NN / 16)   // 6250 fused blocks (NN % 16 == 0)

#define CC 64             // edge chunks
#define CH (EE / CC)      // 12500 edges per chunk
#define HALF 50000        // nodes per LDS histogram (2 ranges)
#define HWORDS 12500      // packed u8 words per histogram (50KB LDS)
#define NWORDS 25000      // packed words per full node array

#define FB (EE / 256)     // 3125 fill blocks in the merged kernel
#define PB (NN * 32 / 256) // 12500 prescale blocks in the merged kernel

typedef __attribute__((ext_vector_type(8))) short short8;
typedef __attribute__((ext_vector_type(4))) float floatx4;

__device__ inline float bf2f(unsigned int u16) {
    union { unsigned int i; float f; } c;
    c.i = u16 << 16;
    return c.f;
}
__device__ inline ushort f2bf(float f) {
    union { float f; unsigned int i; } c;
    c.f = f;
    unsigned int u = c.i;
    return (ushort)((u + 0x7fffu + ((u >> 16) & 1u)) >> 16);  // RNE
}

// ---------------- chunked packed-u8 LDS histograms (+ embedded wconv) ----------------
__global__ __launch_bounds__(512) void count_kernel(const int* __restrict__ row,
                                                    const int* __restrict__ col,
                                                    unsigned int* __restrict__ partial_out,
                                                    unsigned int* __restrict__ partial_in,
                                                    unsigned char* __restrict__ off_u8,
                                                    const float* __restrict__ W1,
                                                    const float* __restrict__ W2,
                                                    ushort* __restrict__ wb1,
                                                    ushort* __restrict__ wb2) {
    __shared__ unsigned int h[HWORDS];
    for (int i = threadIdx.x; i < HWORDS; i += 512) h[i] = 0;
    if (threadIdx.x < 32) {   // embedded wconv: 32 float4 per block
        int i = blockIdx.x * 32 + threadIdx.x;   // 0..8191
        const float* W = (i < 4096) ? W1 : W2;
        ushort* wb = (i < 4096) ? wb1 : wb2;
        int j = i & 4095;
        float4 v = ((const float4*)W)[j];
        ushort4 o;
        o.x = f2bf(v.x); o.y = f2bf(v.y); o.z = f2bf(v.z); o.w = f2bf(v.w);
        ((ushort4*)wb)[j] = o;
    }
    __syncthreads();

    const int kind = blockIdx.x >> 7;          // 0 = in (col), 1 = out (row)
    const int r = (blockIdx.x >> 6) & 1;       // node range
    const int c = blockIdx.x & 63;             // edge chunk
    const int* __restrict__ idx = kind ? row : col;
    const int base = c * CH;
    const int lo = r * HALF;

    for (int t = threadIdx.x; t < CH; t += 512) {
        const int e = base + t;
        const unsigned int d = (unsigned int)(idx[e] - lo);
        if (d < (unsigned int)HALF) {
            const int sh = 8 * (d & 3);
            unsigned int old = atomicAdd(&h[d >> 2], 1u << sh);
            if (kind == 0) off_u8[e] = (unsigned char)((old >> sh) & 0xffu);
        }
    }
    __syncthreads();

    unsigned int* dst = (kind ? partial_out : partial_in) + c * NWORDS + r * HWORDS;
    for (int i = threadIdx.x; i < HWORDS; i += 512) dst[i] = h[i];
}

// ---------------- per-node: totals, dinv, per-chunk packed-u8 prefixes ----------------
__global__ __launch_bounds__(256) void node_kernel(const unsigned int* __restrict__ partial_out,
                                                   const unsigned int* __restrict__ partial_in,
                                                   int* __restrict__ cnt_total,
                                                   unsigned int* __restrict__ xoff,
                                                   float* __restrict__ dinv_out,
                                                   float* __restrict__ dinv_in) {
    const int w = blockIdx.x * 256 + threadIdx.x;
    if (w >= NWORDS) return;
    unsigned int prefix = 0;   // packed running prefix (4 nodes)
    unsigned int tot_out = 0;  // packed out-degree totals
#pragma unroll
    for (int c = 0; c < CC; ++c) {
        unsigned int v = partial_in[c * NWORDS + w];
        xoff[c * NWORDS + w] = prefix;
        prefix += v;
        tot_out += partial_out[c * NWORDS + w];
    }
    int4 ct;
    float4 fi, fo;
#pragma unroll
    for (int j = 0; j < 4; ++j) {
        int din  = (int)((prefix  >> (8 * j)) & 0xffu);
        int dout = (int)((tot_out >> (8 * j)) & 0xffu);
        ((int*)&ct)[j]   = din;
        ((float*)&fi)[j] = rsqrtf((float)max(din, 1));
        ((float*)&fo)[j] = rsqrtf((float)max(dout, 1));
    }
    ((int4*)cnt_total)[w] = ct;
    ((float4*)dinv_in)[w] = fi;
    ((float4*)dinv_out)[w] = fo;
}

// ---------------- exclusive scan of cnt_total (2 levels; combine inlined) ----------------
__global__ __launch_bounds__(256) void scan1_kernel(const int* __restrict__ cnt,
                                                    int* __restrict__ excl,
                                                    int* __restrict__ bsums) {
    __shared__ int tmp[256];
    const int t = threadIdx.x;
    const int base = blockIdx.x * 1024 + t * 4;
    int a[4];
#pragma unroll
    for (int q = 0; q < 4; ++q) a[q] = (base + q < NN) ? cnt[base + q] : 0;
    int s = a[0] + a[1] + a[2] + a[3];
    tmp[t] = s;
    __syncthreads();
    for (int off = 1; off < 256; off <<= 1) {
        int v = 0;
        if (t >= off) v = tmp[t - off];
        __syncthreads();
        tmp[t] += v;
        __syncthreads();
    }
    int excl_s = tmp[t] - s;
    if (t == 255) bsums[blockIdx.x] = tmp[t];
    int run = excl_s;
#pragma unroll
    for (int q = 0; q < 4; ++q) {
        if (base + q < NN) excl[base + q] = run;
        run += a[q];
    }
}

__global__ __launch_bounds__(256) void scan2_kernel(int* __restrict__ bsums, int nb) {
    __shared__ int tmp[256];
    const int t = threadIdx.x;
    int s = (t < nb) ? bsums[t] : 0;
    tmp[t] = s;
    __syncthreads();
    for (int off = 1; off < 256; off <<= 1) {
        int v = 0;
        if (t >= off) v = tmp[t - off];
        __syncthreads();
        tmp[t] += v;
        __syncthreads();
    }
    if (t < nb) bsums[t] = tmp[t] - s;   // exclusive
}

// row_start(n) == excl[n] + bsums[n >> 10]  (bsums: 392B, L1-resident)

// ---------------- merged: atomic-free CSR fill (blocks < FB) + prescale ----------------
__global__ __launch_bounds__(256) void fill_prescale_kernel(const int* __restrict__ row,
                                                            const int* __restrict__ col,
                                                            const int* __restrict__ excl,
                                                            const int* __restrict__ bsums,
                                                            const unsigned char* __restrict__ xoff_u8,
                                                            const unsigned char* __restrict__ off_u8,
                                                            int* __restrict__ srcs,
                                                            const float* __restrict__ x,
                                                            const float* __restrict__ dinv_out,
                                                            ushort* __restrict__ xb) {
    if (blockIdx.x < FB) {
        // ---- fill: one edge per thread ----
        int e = blockIdx.x * 256 + threadIdx.x;   // EE % 256 == 0
        const int cl = col[e];
        const int c = e / CH;                     // chunk id
        const int rs = excl[cl] + bsums[cl >> 10];
        srcs[rs + (int)xoff_u8[(size_t)c * NN + cl] + (int)off_u8[e]] = row[e];
    } else {
        // ---- prescale: one float4 per thread ----
        int idx = (blockIdx.x - FB) * 256 + threadIdx.x;   // NN*32 % 256 == 0
        int n = idx >> 5;
        float s = dinv_out[n];
        float4 v = ((const float4*)x)[idx];
        ushort4 o;
        o.x = f2bf(v.x * s);
        o.y = f2bf(v.y * s);
        o.z = f2bf(v.z * s);
        o.w = f2bf(v.w * s);
        ((ushort4*)xb)[idx] = o;
    }
}

// ---------------- fused gather + MFMA + epilogue (one 16-node tile/block) ----------------
// Phase 1: 16 nodes x 16 lanes, identical inner loop to the R14 standalone
// gather, result to a 4.4KB LDS A-tile (stride 136 ushort: 2-way banks).
// Phase 2 (after ONE barrier): wave w computes output cols [32w, 32w+32)
// (t = 2w, 2w+1): A-frags from LDS, B-frags from global wb (L1-resident).
template <bool L1>
__global__ __launch_bounds__(256) void gather_gemm(const ushort* __restrict__ src,
                                                   const int* __restrict__ excl,
                                                   const int* __restrict__ bsums,
                                                   const int* __restrict__ srcs,
                                                   const ushort* __restrict__ wb,
                                                   const float* __restrict__ bias,
                                                   const float* __restrict__ dinv_in,
                                                   const float* __restrict__ dinv_out,
                                                   const float* __restrict__ x,
                                                   ushort* __restrict__ hs,
                                                   float* __restrict__ out) {
    __shared__ ushort At[16 * 136];   // 4352 B

    {   // ---- phase 1: gather (node = tile row), one pass ----
        const int nl = threadIdx.x >> 4;          // 0..15
        const int lane16 = threadIdx.x & 15;
        const int node = blockIdx.x * 16 + nl;    // grid == NTILE, NN%16==0
        int p = excl[node] + bsums[node >> 10];
        const int end = (node + 1 < NN) ? excl[node + 1] + bsums[(node + 1) >> 10] : EE;
        float a0 = 0.f, a1 = 0.f, a2 = 0.f, a3 = 0.f;
        float a4 = 0.f, a5 = 0.f, a6 = 0.f, a7 = 0.f;

#define ACCUM(V)                                     \
    do {                                             \
        a0 += bf2f((V).x & 0xffffu);                 \
        a1 += bf2f((V).x >> 16);                     \
        a2 += bf2f((V).y & 0xffffu);                 \
        a3 += bf2f((V).y >> 16);                     \
        a4 += bf2f((V).z & 0xffffu);                 \
        a5 += bf2f((V).z >> 16);                     \
        a6 += bf2f((V).w & 0xffffu);                 \
        a7 += bf2f((V).w >> 16);                     \
    } while (0)

        for (; p + 3 < end; p += 4) {
            int s0 = srcs[p];
            int s1 = srcs[p + 1];
            int s2 = srcs[p + 2];
            int s3 = srcs[p + 3];
            uint4 v0 = ((const uint4*)(src + (size_t)s0 * DD))[lane16];
            uint4 v1 = ((const uint4*)(src + (size_t)s1 * DD))[lane16];
            uint4 v2 = ((const uint4*)(src + (size_t)s2 * DD))[lane16];
            uint4 v3 = ((const uint4*)(src + (size_t)s3 * DD))[lane16];
            ACCUM(v0); ACCUM(v1); ACCUM(v2); ACCUM(v3);
        }
        for (; p < end; ++p) {
            int s0 = srcs[p];
            uint4 v0 = ((const uint4*)(src + (size_t)s0 * DD))[lane16];
            ACCUM(v0);
        }
#undef ACCUM

        uint4 o;
        o.x = (unsigned int)f2bf(a0) | ((unsigned int)f2bf(a1) << 16);
        o.y = (unsigned int)f2bf(a2) | ((unsigned int)f2bf(a3) << 16);
        o.z = (unsigned int)f2bf(a4) | ((unsigned int)f2bf(a5) << 16);
        o.w = (unsigned int)f2bf(a6) | ((unsigned int)f2bf(a7) << 16);
        *(uint4*)(At + nl * 136 + lane16 * 8) = o;
    }
    __syncthreads();

    // ---- phase 2: MFMA, all 4 waves (wave w -> cols [32w, 32w+32)) ----
    const int wave = threadIdx.x >> 6;
    const int lane = threadIdx.x & 63;
    const int mi = lane & 15;
    const int quad = lane >> 4;
    const int m0 = blockIdx.x * 16;
    const int t0 = wave * 2;

    floatx4 acc0 = (floatx4){0.f, 0.f, 0.f, 0.f};
    floatx4 acc1 = (floatx4){0.f, 0.f, 0.f, 0.f};
    const ushort* ap = At + mi * 136 + quad * 8;
    const ushort* bp = wb + (size_t)mi * DD + quad * 8;
#pragma unroll
    for (int s = 0; s < 4; ++s) {
        short8 a  = *(const short8*)(ap + s * 32);
        short8 b0 = *(const short8*)(bp + (size_t)(t0 * 16) * DD + s * 32);
        short8 b1 = *(const short8*)(bp + (size_t)(t0 * 16 + 16) * DD + s * 32);
        acc0 = __builtin_amdgcn_mfma_f32_16x16x32_bf16(a, b0, acc0, 0, 0, 0);
        acc1 = __builtin_amdgcn_mfma_f32_16x16x32_bf16(a, b1, acc1, 0, 0, 0);
    }

    // C/D layout: col = lane&15, row = quad*4 + reg
    float dv[4], dov[4];
#pragma unroll
    for (int i = 0; i < 4; ++i) {
        int r = m0 + quad * 4 + i;
        dv[i] = dinv_in[r];
        if (L1) dov[i] = dinv_out[r];
    }
#pragma unroll
    for (int u = 0; u < 2; ++u) {
        const int c = (t0 + u) * 16 + mi;
        const float bv = bias[c];
        const floatx4 av = u ? acc1 : acc0;
#pragma unroll
        for (int i = 0; i < 4; ++i) {
            int r = m0 + quad * 4 + i;
            float o = (av[i] + bv) * dv[i];
            if (L1) {
                o += x[(size_t)r * DD + c];
                o = fmaxf(o, 0.f);
                hs[(size_t)r * DD + c] = f2bf(o * dov[i]);
            } else {
                out[(size_t)r * DD + c] = o;
            }
        }
    }
}

extern "C" void kernel_launch(void* const* d_in, const int* in_sizes, int n_in,
                              void* d_out, int out_size, void* d_ws, size_t ws_size,
                              hipStream_t stream) {
    const float* x  = (const float*)d_in[0];
    const int*   ei = (const int*)d_in[1];
    const float* W1 = (const float*)d_in[2];
    const float* b1 = (const float*)d_in[3];
    const float* W2 = (const float*)d_in[4];
    const float* b2 = (const float*)d_in[5];
    float* out = (float*)d_out;

    const int* row = ei;        // edge_index[0] (source)
    const int* col = ei + EE;   // edge_index[1] (target)

    // workspace layout. The h1 region (old agg, 25.6MB) hosts the CSR-build
    // temporaries (off_u8 0.8MB, partial_in/out 6.4MB each, xoff 6.4MB),
    // all dead after fill; layer 1's fused kernel then writes hs there
    // (it cannot write its own gather source xb). No memset anywhere.
    ushort* h1      = (ushort*)d_ws;                 // N*DD bf16 (25.6 MB)
    ushort* xb      = h1 + (size_t)NN * DD;          // N*DD bf16 (25.6 MB)
    float* dinv_out = (float*)(xb + (size_t)NN * DD);
    float* dinv_in  = dinv_out + NN;
    int*   cnt      = (int*)(dinv_in + NN);          // N (cnt_total for scan)
    int*   excl     = cnt + NN;                      // N
    int*   srcs     = excl + NN;                     // E
    int*   bsums    = srcs + EE;                     // 256
    ushort* wb1     = (ushort*)(bsums + 256);        // 128*128 bf16 (32 KB)
    ushort* wb2     = wb1 + DD * DD;                 // 128*128 bf16 (32 KB)

    unsigned char* off_u8      = (unsigned char*)h1;               // E bytes (aliased)
    unsigned int*  partial_in  = (unsigned int*)(off_u8 + EE);     // CC*NWORDS (aliased)
    unsigned int*  partial_out = partial_in + CC * NWORDS;         // CC*NWORDS (aliased)
    unsigned int*  xoff        = partial_out + CC * NWORDS;        // CC*NWORDS (aliased)

    // ---- CSR build (+ embedded wconv), 4 launches ----
    count_kernel<<<256, 512, 0, stream>>>(row, col, partial_out, partial_in, off_u8,
                                          W1, W2, wb1, wb2);
    node_kernel<<<(NWORDS + 255) / 256, 256, 0, stream>>>(partial_out, partial_in, cnt, xoff,
                                                          dinv_out, dinv_in);
    scan1_kernel<<<NB1, 256, 0, stream>>>(cnt, excl, bsums);
    scan2_kernel<<<1, 256, 0, stream>>>(bsums, NB1);

    // ---- fill + prescale (merged, 1 launch) ----
    fill_prescale_kernel<<<FB + PB, 256, 0, stream>>>(row, col, excl, bsums,
                                                      (const unsigned char*)xoff, off_u8, srcs,
                                                      x, dinv_out, xb);

    // ---- layer 1: fused gather+GEMM (xb -> h1) ----
    gather_gemm<true><<<NTILE, 256, 0, stream>>>(xb, excl, bsums, srcs, wb1, b1,
                                                 dinv_in, dinv_out, x, /*hs=*/h1, nullptr);

    // ---- layer 2: fused gather+GEMM (h1 -> out) ----
    gather_gemm<false><<<NTILE, 256, 0, stream>>>(h1, excl, bsums, srcs, wb2, b2,
                                                  dinv_in, nullptr, nullptr, nullptr, out);
}

// Round 12
// 268.210 us; speedup vs baseline: 1.0207x; 1.0207x over previous
//
#include <hip/hip_runtime.h>

// GCN: N=100000, E=800000, D=128, two GraphConv layers.
// R16 = R14 (best: 264.3us) + ONE change: gemm_ep moves to 512-thread
// blocks (8 waves, 8 tiles/block). Ws (34.8KB) allows only 4 blocks/CU in
// the 160KB LDS; at 256 thr/block that capped gemm at 16 waves/CU (50%).
// 512 thr/block: same LDS, 4 blocks/CU = 32 waves/CU, and wb staging
// traffic + barriers halve (1563 -> 782 blocks). MFMA loop + epilogue
// byte-identical.
//  - R15 lesson: fusion loses at BOTH granularities (R9: 64-node barrier,
//    R15: 16-node barrier + LDS conflicts + occupancy 53% > the 51MB/layer
//    round-trip saved). Gather is latency-bound at the L3 random-row floor
//    (30% HBM, 25% VALU) - its structure is final.
// Everything else byte-identical to R14.

#define NN 100000
#define EE 800000
#define DD 128
#define NB1 98            // ceil(NN / 1024) blocks for scan level 1
#define NTILE (NN / 16)   // 6250 MFMA row-tiles (NN % 16 == 0)

#define CC 64             // edge chunks
#define CH (EE / CC)      // 12500 edges per chunk
#define HALF 50000        // nodes per LDS histogram (2 ranges)
#define HWORDS 12500      // packed u8 words per histogram (50KB LDS)
#define NWORDS 25000      // packed words per full node array

#define FB (EE / 256)     // 3125 fill blocks in the merged kernel
#define PB (NN * 32 / 256) // 12500 prescale blocks in the merged kernel

typedef __attribute__((ext_vector_type(8))) short short8;
typedef __attribute__((ext_vector_type(4))) float floatx4;

__device__ inline float bf2f(unsigned int u16) {
    union { unsigned int i; float f; } c;
    c.i = u16 << 16;
    return c.f;
}
__device__ inline ushort f2bf(float f) {
    union { float f; unsigned int i; } c;
    c.f = f;
    unsigned int u = c.i;
    return (ushort)((u + 0x7fffu + ((u >> 16) & 1u)) >> 16);  // RNE
}

// ---------------- chunked packed-u8 LDS histograms (+ embedded wconv) ----------------
__global__ __launch_bounds__(512) void count_kernel(const int* __restrict__ row,
                                                    const int* __restrict__ col,
                                                    unsigned int* __restrict__ partial_out,
                                                    unsigned int* __restrict__ partial_in,
                                                    unsigned char* __restrict__ off_u8,
                                                    const float* __restrict__ W1,
                                                    const float* __restrict__ W2,
                                                    ushort* __restrict__ wb1,
                                                    ushort* __restrict__ wb2) {
    __shared__ unsigned int h[HWORDS];
    for (int i = threadIdx.x; i < HWORDS; i += 512) h[i] = 0;
    if (threadIdx.x < 32) {   // embedded wconv: 32 float4 per block
        int i = blockIdx.x * 32 + threadIdx.x;   // 0..8191
        const float* W = (i < 4096) ? W1 : W2;
        ushort* wb = (i < 4096) ? wb1 : wb2;
        int j = i & 4095;
        float4 v = ((const float4*)W)[j];
        ushort4 o;
        o.x = f2bf(v.x); o.y = f2bf(v.y); o.z = f2bf(v.z); o.w = f2bf(v.w);
        ((ushort4*)wb)[j] = o;
    }
    __syncthreads();

    const int kind = blockIdx.x >> 7;          // 0 = in (col), 1 = out (row)
    const int r = (blockIdx.x >> 6) & 1;       // node range
    const int c = blockIdx.x & 63;             // edge chunk
    const int* __restrict__ idx = kind ? row : col;
    const int base = c * CH;
    const int lo = r * HALF;

    for (int t = threadIdx.x; t < CH; t += 512) {
        const int e = base + t;
        const unsigned int d = (unsigned int)(idx[e] - lo);
        if (d < (unsigned int)HALF) {
            const int sh = 8 * (d & 3);
            unsigned int old = atomicAdd(&h[d >> 2], 1u << sh);
            if (kind == 0) off_u8[e] = (unsigned char)((old >> sh) & 0xffu);
        }
    }
    __syncthreads();

    unsigned int* dst = (kind ? partial_out : partial_in) + c * NWORDS + r * HWORDS;
    for (int i = threadIdx.x; i < HWORDS; i += 512) dst[i] = h[i];
}

// ---------------- per-node: totals, dinv, per-chunk packed-u8 prefixes ----------------
__global__ __launch_bounds__(256) void node_kernel(const unsigned int* __restrict__ partial_out,
                                                   const unsigned int* __restrict__ partial_in,
                                                   int* __restrict__ cnt_total,
                                                   unsigned int* __restrict__ xoff,
                                                   float* __restrict__ dinv_out,
                                                   float* __restrict__ dinv_in) {
    const int w = blockIdx.x * 256 + threadIdx.x;
    if (w >= NWORDS) return;
    unsigned int prefix = 0;   // packed running prefix (4 nodes)
    unsigned int tot_out = 0;  // packed out-degree totals
#pragma unroll
    for (int c = 0; c < CC; ++c) {
        unsigned int v = partial_in[c * NWORDS + w];
        xoff[c * NWORDS + w] = prefix;
        prefix += v;
        tot_out += partial_out[c * NWORDS + w];
    }
    int4 ct;
    float4 fi, fo;
#pragma unroll
    for (int j = 0; j < 4; ++j) {
        int din  = (int)((prefix  >> (8 * j)) & 0xffu);
        int dout = (int)((tot_out >> (8 * j)) & 0xffu);
        ((int*)&ct)[j]   = din;
        ((float*)&fi)[j] = rsqrtf((float)max(din, 1));
        ((float*)&fo)[j] = rsqrtf((float)max(dout, 1));
    }
    ((int4*)cnt_total)[w] = ct;
    ((float4*)dinv_in)[w] = fi;
    ((float4*)dinv_out)[w] = fo;
}

// ---------------- exclusive scan of cnt_total (2 levels; combine inlined) ----------------
__global__ __launch_bounds__(256) void scan1_kernel(const int* __restrict__ cnt,
                                                    int* __restrict__ excl,
                                                    int* __restrict__ bsums) {
    __shared__ int tmp[256];
    const int t = threadIdx.x;
    const int base = blockIdx.x * 1024 + t * 4;
    int a[4];
#pragma unroll
    for (int q = 0; q < 4; ++q) a[q] = (base + q < NN) ? cnt[base + q] : 0;
    int s = a[0] + a[1] + a[2] + a[3];
    tmp[t] = s;
    __syncthreads();
    for (int off = 1; off < 256; off <<= 1) {
        int v = 0;
        if (t >= off) v = tmp[t - off];
        __syncthreads();
        tmp[t] += v;
        __syncthreads();
    }
    int excl_s = tmp[t] - s;
    if (t == 255) bsums[blockIdx.x] = tmp[t];
    int run = excl_s;
#pragma unroll
    for (int q = 0; q < 4; ++q) {
        if (base + q < NN) excl[base + q] = run;
        run += a[q];
    }
}

__global__ __launch_bounds__(256) void scan2_kernel(int* __restrict__ bsums, int nb) {
    __shared__ int tmp[256];
    const int t = threadIdx.x;
    int s = (t < nb) ? bsums[t] : 0;
    tmp[t] = s;
    __syncthreads();
    for (int off = 1; off < 256; off <<= 1) {
        int v = 0;
        if (t >= off) v = tmp[t - off];
        __syncthreads();
        tmp[t] += v;
        __syncthreads();
    }
    if (t < nb) bsums[t] = tmp[t] - s;   // exclusive
}

// row_start(n) == excl[n] + bsums[n >> 10]  (bsums: 392B, L1-resident)

// ---------------- merged: atomic-free CSR fill (blocks < FB) + prescale ----------------
__global__ __launch_bounds__(256) void fill_prescale_kernel(const int* __restrict__ row,
                                                            const int* __restrict__ col,
                                                            const int* __restrict__ excl,
                                                            const int* __restrict__ bsums,
                                                            const unsigned char* __restrict__ xoff_u8,
                                                            const unsigned char* __restrict__ off_u8,
                                                            int* __restrict__ srcs,
                                                            const float* __restrict__ x,
                                                            const float* __restrict__ dinv_out,
                                                            ushort* __restrict__ xb) {
    if (blockIdx.x < FB) {
        // ---- fill: one edge per thread ----
        int e = blockIdx.x * 256 + threadIdx.x;   // EE % 256 == 0
        const int cl = col[e];
        const int c = e / CH;                     // chunk id
        const int rs = excl[cl] + bsums[cl >> 10];
        srcs[rs + (int)xoff_u8[(size_t)c * NN + cl] + (int)off_u8[e]] = row[e];
    } else {
        // ---- prescale: one float4 per thread ----
        int idx = (blockIdx.x - FB) * 256 + threadIdx.x;   // NN*32 % 256 == 0
        int n = idx >> 5;
        float s = dinv_out[n];
        float4 v = ((const float4*)x)[idx];
        ushort4 o;
        o.x = f2bf(v.x * s);
        o.y = f2bf(v.y * s);
        o.z = f2bf(v.z * s);
        o.w = f2bf(v.w * s);
        ((ushort4*)xb)[idx] = o;
    }
}

// ---------------- gather: 16 lanes/node, uint4 (16B) per lane, 4-edge unroll ----------------
__global__ __launch_bounds__(256) void gather_kernel(const ushort* __restrict__ src,
                                                     const int* __restrict__ excl,
                                                     const int* __restrict__ bsums,
                                                     const int* __restrict__ srcs,
                                                     ushort* __restrict__ agg) {
    const int node = blockIdx.x * 16 + (threadIdx.x >> 4);
    const int lane = threadIdx.x & 15;
    if (node >= NN) return;
    int p = excl[node] + bsums[node >> 10];
    const int end = (node + 1 < NN) ? excl[node + 1] + bsums[(node + 1) >> 10] : EE;
    float a0 = 0.f, a1 = 0.f, a2 = 0.f, a3 = 0.f;
    float a4 = 0.f, a5 = 0.f, a6 = 0.f, a7 = 0.f;

#define ACCUM(V)                                     \
    do {                                             \
        a0 += bf2f((V).x & 0xffffu);                 \
        a1 += bf2f((V).x >> 16);                     \
        a2 += bf2f((V).y & 0xffffu);                 \
        a3 += bf2f((V).y >> 16);                     \
        a4 += bf2f((V).z & 0xffffu);                 \
        a5 += bf2f((V).z >> 16);                     \
        a6 += bf2f((V).w & 0xffffu);                 \
        a7 += bf2f((V).w >> 16);                     \
    } while (0)

    for (; p + 3 < end; p += 4) {
        int s0 = srcs[p];
        int s1 = srcs[p + 1];
        int s2 = srcs[p + 2];
        int s3 = srcs[p + 3];
        uint4 v0 = ((const uint4*)(src + (size_t)s0 * DD))[lane];
        uint4 v1 = ((const uint4*)(src + (size_t)s1 * DD))[lane];
        uint4 v2 = ((const uint4*)(src + (size_t)s2 * DD))[lane];
        uint4 v3 = ((const uint4*)(src + (size_t)s3 * DD))[lane];
        ACCUM(v0); ACCUM(v1); ACCUM(v2); ACCUM(v3);
    }
    for (; p < end; ++p) {
        int s0 = srcs[p];
        uint4 v0 = ((const uint4*)(src + (size_t)s0 * DD))[lane];
        ACCUM(v0);
    }
#undef ACCUM

    uint4 o;
    o.x = (unsigned int)f2bf(a0) | ((unsigned int)f2bf(a1) << 16);
    o.y = (unsigned int)f2bf(a2) | ((unsigned int)f2bf(a3) << 16);
    o.z = (unsigned int)f2bf(a4) | ((unsigned int)f2bf(a5) << 16);
    o.w = (unsigned int)f2bf(a6) | ((unsigned int)f2bf(a7) << 16);
    ((uint4*)(agg + (size_t)node * DD))[lane] = o;
}

// ---------------- MFMA bf16 GEMM + epilogue (512 threads = 8 waves/block) ----------------
// C[m, j] = sum_k agg[m,k] * wb[j,k]   (wb row-major [j][k] == B^T input)
// Block: 512 threads = 8 waves, each wave one 16-row tile x all 128 cols.
// wb (bf16) staged into LDS once per 8 tiles; rows padded to 136.
// 34.8KB LDS -> 4 blocks/CU = 32 waves/CU (vs 16 at 256 thr/block).
template <bool L1>
__global__ __launch_bounds__(512) void gemm_ep(const ushort* __restrict__ agg,
                                               const ushort* __restrict__ wb,
                                               const float* __restrict__ bias,
                                               const float* __restrict__ dinv_in,
                                               const float* __restrict__ dinv_out,
                                               const float* __restrict__ x,
                                               ushort* __restrict__ hs,
                                               float* __restrict__ out) {
    __shared__ ushort Ws[128 * 136];
    {   // stage wb (already bf16) into LDS: 64B per thread = 4 x uint4
        int j = threadIdx.x >> 2;                 // 0..127
        int k0 = (threadIdx.x & 3) * 32;          // 0,32,64,96 (ushorts)
        const uint4* wp = (const uint4*)(wb + (size_t)j * DD + k0);
        uint4* dst = (uint4*)(Ws + j * 136 + k0);
#pragma unroll
        for (int q = 0; q < 4; ++q) dst[q] = wp[q];
    }
    __syncthreads();

    const int wave = threadIdx.x >> 6;            // 0..7
    const int lane = threadIdx.x & 63;
    const int tile = blockIdx.x * 8 + wave;
    if (tile >= NTILE) return;
    const int mi = lane & 15;
    const int quad = lane >> 4;
    const int m0 = tile * 16;

    floatx4 acc[8];
#pragma unroll
    for (int t = 0; t < 8; ++t) acc[t] = (floatx4){0.f, 0.f, 0.f, 0.f};

    const ushort* ap = agg + (size_t)(m0 + mi) * DD + quad * 8;
#pragma unroll
    for (int s = 0; s < 4; ++s) {
        short8 a = *(const short8*)(ap + s * 32);
#pragma unroll
        for (int t = 0; t < 8; ++t) {
            short8 b = *(const short8*)(Ws + (t * 16 + mi) * 136 + s * 32 + quad * 8);
            acc[t] = __builtin_amdgcn_mfma_f32_16x16x32_bf16(a, b, acc[t], 0, 0, 0);
        }
    }

    // C/D layout: col = lane&15, row = quad*4 + reg
    float dv[4], dov[4];
#pragma unroll
    for (int i = 0; i < 4; ++i) {
        int r = m0 + quad * 4 + i;
        dv[i] = dinv_in[r];
        if (L1) dov[i] = dinv_out[r];
    }
#pragma unroll
    for (int t = 0; t < 8; ++t) {
        int c = t * 16 + mi;
        float bv = bias[c];
#pragma unroll
        for (int i = 0; i < 4; ++i) {
            int r = m0 + quad * 4 + i;
            float o = (acc[t][i] + bv) * dv[i];
            if (L1) {
                o += x[(size_t)r * DD + c];
                o = fmaxf(o, 0.f);
                hs[(size_t)r * DD + c] = f2bf(o * dov[i]);
            } else {
                out[(size_t)r * DD + c] = o;
            }
        }
    }
}

extern "C" void kernel_launch(void* const* d_in, const int* in_sizes, int n_in,
                              void* d_out, int out_size, void* d_ws, size_t ws_size,
                              hipStream_t stream) {
    const float* x  = (const float*)d_in[0];
    const int*   ei = (const int*)d_in[1];
    const float* W1 = (const float*)d_in[2];
    const float* b1 = (const float*)d_in[3];
    const float* W2 = (const float*)d_in[4];
    const float* b2 = (const float*)d_in[5];
    float* out = (float*)d_out;

    const int* row = ei;        // edge_index[0] (source)
    const int* col = ei + EE;   // edge_index[1] (target)

    // workspace layout. The agg region (25.6MB) hosts the CSR-build
    // temporaries (off_u8 0.8MB, partial_in/out 6.4MB each, xoff 6.4MB),
    // all dead before the first gather writes agg. No memset anywhere.
    ushort* agg     = (ushort*)d_ws;                 // N*DD bf16 (25.6 MB)
    ushort* xb      = agg + (size_t)NN * DD;         // N*DD bf16 (25.6 MB) -> becomes hs
    float* dinv_out = (float*)(xb + (size_t)NN * DD);
    float* dinv_in  = dinv_out + NN;
    int*   cnt      = (int*)(dinv_in + NN);          // N (cnt_total for scan)
    int*   excl     = cnt + NN;                      // N
    int*   srcs     = excl + NN;                     // E
    int*   bsums    = srcs + EE;                     // 256
    ushort* wb1     = (ushort*)(bsums + 256);        // 128*128 bf16 (32 KB)
    ushort* wb2     = wb1 + DD * DD;                 // 128*128 bf16 (32 KB)

    unsigned char* off_u8      = (unsigned char*)agg;              // E bytes (aliased)
    unsigned int*  partial_in  = (unsigned int*)(off_u8 + EE);     // CC*NWORDS (aliased)
    unsigned int*  partial_out = partial_in + CC * NWORDS;         // CC*NWORDS (aliased)
    unsigned int*  xoff        = partial_out + CC * NWORDS;        // CC*NWORDS (aliased)

    // ---- CSR build (+ embedded wconv), 4 launches ----
    count_kernel<<<256, 512, 0, stream>>>(row, col, partial_out, partial_in, off_u8,
                                          W1, W2, wb1, wb2);
    node_kernel<<<(NWORDS + 255) / 256, 256, 0, stream>>>(partial_out, partial_in, cnt, xoff,
                                                          dinv_out, dinv_in);
    scan1_kernel<<<NB1, 256, 0, stream>>>(cnt, excl, bsums);
    scan2_kernel<<<1, 256, 0, stream>>>(bsums, NB1);

    // ---- fill + prescale (merged, 1 launch) ----
    fill_prescale_kernel<<<FB + PB, 256, 0, stream>>>(row, col, excl, bsums,
                                                      (const unsigned char*)xoff, off_u8, srcs,
                                                      x, dinv_out, xb);

    // ---- layer 1 ----
    gather_kernel<<<(NN + 15) / 16, 256, 0, stream>>>(xb, excl, bsums, srcs, agg);
    gemm_ep<true><<<(NTILE + 7) / 8, 512, 0, stream>>>(agg, wb1, b1, dinv_in, dinv_out, x,
                                                       /*hs=*/xb, /*out=*/nullptr);

    // ---- layer 2 ----
    gather_kernel<<<(NN + 15) / 16, 256, 0, stream>>>(xb, excl, bsums, srcs, agg);
    gemm_ep<false><<<(NTILE + 7) / 8, 512, 0, stream>>>(agg, wb2, b2, dinv_in, nullptr, nullptr,
                                                        nullptr, out);
}

// Round 13
// 263.794 us; speedup vs baseline: 1.0378x; 1.0167x over previous
//
#include <hip/hip_runtime.h>

// GCN: N=100000, E=800000, D=128, two GraphConv layers.
// R17 = exact R14 restore (best measured: 264.3us). R16's 512-thread gemm
// regressed (+3.9us); R14 is the verified optimum of the explored space:
//  - CSR build: chunk-axis packed-u8 LDS histograms, zero global atomics
//    (global atomics are memory-side on gfx950 regardless of scope, R5/R6)
//  - gather: 16 lanes/node, uint4, 4-edge unroll (R12: less MLP -22us,
//    R13: more MLP -7us; this is the L3 random-row latency floor)
//  - gemm: 256-thr blocks, bf16 wb staged to LDS (R10: global-B -40us,
//    R16: 512-thr -4us), MFMA 16x16x32, fused epilogue
//  - fusion falsified at 64-node (R9) and 16-node (R15) granularity
//  - launches consolidated 13 -> 9 (wconv in count, scan3 inlined,
//    fill+prescale merged)

#define NN 100000
#define EE 800000
#define DD 128
#define NB1 98            // ceil(NN / 1024) blocks for scan level 1
#define NTILE (NN / 16)   // 6250 MFMA row-tiles (NN % 16 == 0)

#define CC 64             // edge chunks
#define CH (EE / CC)      // 12500 edges per chunk
#define HALF 50000        // nodes per LDS histogram (2 ranges)
#define HWORDS 12500      // packed u8 words per histogram (50KB LDS)
#define NWORDS 25000      // packed words per full node array

#define FB (EE / 256)     // 3125 fill blocks in the merged kernel
#define PB (NN * 32 / 256) // 12500 prescale blocks in the merged kernel

typedef __attribute__((ext_vector_type(8))) short short8;
typedef __attribute__((ext_vector_type(4))) float floatx4;

__device__ inline float bf2f(unsigned int u16) {
    union { unsigned int i; float f; } c;
    c.i = u16 << 16;
    return c.f;
}
__device__ inline ushort f2bf(float f) {
    union { float f; unsigned int i; } c;
    c.f = f;
    unsigned int u = c.i;
    return (ushort)((u + 0x7fffu + ((u >> 16) & 1u)) >> 16);  // RNE
}

// ---------------- chunked packed-u8 LDS histograms (+ embedded wconv) ----------------
__global__ __launch_bounds__(512) void count_kernel(const int* __restrict__ row,
                                                    const int* __restrict__ col,
                                                    unsigned int* __restrict__ partial_out,
                                                    unsigned int* __restrict__ partial_in,
                                                    unsigned char* __restrict__ off_u8,
                                                    const float* __restrict__ W1,
                                                    const float* __restrict__ W2,
                                                    ushort* __restrict__ wb1,
                                                    ushort* __restrict__ wb2) {
    __shared__ unsigned int h[HWORDS];
    for (int i = threadIdx.x; i < HWORDS; i += 512) h[i] = 0;
    if (threadIdx.x < 32) {   // embedded wconv: 32 float4 per block
        int i = blockIdx.x * 32 + threadIdx.x;   // 0..8191
        const float* W = (i < 4096) ? W1 : W2;
        ushort* wb = (i < 4096) ? wb1 : wb2;
        int j = i & 4095;
        float4 v = ((const float4*)W)[j];
        ushort4 o;
        o.x = f2bf(v.x); o.y = f2bf(v.y); o.z = f2bf(v.z); o.w = f2bf(v.w);
        ((ushort4*)wb)[j] = o;
    }
    __syncthreads();

    const int kind = blockIdx.x >> 7;          // 0 = in (col), 1 = out (row)
    const int r = (blockIdx.x >> 6) & 1;       // node range
    const int c = blockIdx.x & 63;             // edge chunk
    const int* __restrict__ idx = kind ? row : col;
    const int base = c * CH;
    const int lo = r * HALF;

    for (int t = threadIdx.x; t < CH; t += 512) {
        const int e = base + t;
        const unsigned int d = (unsigned int)(idx[e] - lo);
        if (d < (unsigned int)HALF) {
            const int sh = 8 * (d & 3);
            unsigned int old = atomicAdd(&h[d >> 2], 1u << sh);
            if (kind == 0) off_u8[e] = (unsigned char)((old >> sh) & 0xffu);
        }
    }
    __syncthreads();

    unsigned int* dst = (kind ? partial_out : partial_in) + c * NWORDS + r * HWORDS;
    for (int i = threadIdx.x; i < HWORDS; i += 512) dst[i] = h[i];
}

// ---------------- per-node: totals, dinv, per-chunk packed-u8 prefixes ----------------
__global__ __launch_bounds__(256) void node_kernel(const unsigned int* __restrict__ partial_out,
                                                   const unsigned int* __restrict__ partial_in,
                                                   int* __restrict__ cnt_total,
                                                   unsigned int* __restrict__ xoff,
                                                   float* __restrict__ dinv_out,
                                                   float* __restrict__ dinv_in) {
    const int w = blockIdx.x * 256 + threadIdx.x;
    if (w >= NWORDS) return;
    unsigned int prefix = 0;   // packed running prefix (4 nodes)
    unsigned int tot_out = 0;  // packed out-degree totals
#pragma unroll
    for (int c = 0; c < CC; ++c) {
        unsigned int v = partial_in[c * NWORDS + w];
        xoff[c * NWORDS + w] = prefix;
        prefix += v;
        tot_out += partial_out[c * NWORDS + w];
    }
    int4 ct;
    float4 fi, fo;
#pragma unroll
    for (int j = 0; j < 4; ++j) {
        int din  = (int)((prefix  >> (8 * j)) & 0xffu);
        int dout = (int)((tot_out >> (8 * j)) & 0xffu);
        ((int*)&ct)[j]   = din;
        ((float*)&fi)[j] = rsqrtf((float)max(din, 1));
        ((float*)&fo)[j] = rsqrtf((float)max(dout, 1));
    }
    ((int4*)cnt_total)[w] = ct;
    ((float4*)dinv_in)[w] = fi;
    ((float4*)dinv_out)[w] = fo;
}

// ---------------- exclusive scan of cnt_total (2 levels; combine inlined) ----------------
__global__ __launch_bounds__(256) void scan1_kernel(const int* __restrict__ cnt,
                                                    int* __restrict__ excl,
                                                    int* __restrict__ bsums) {
    __shared__ int tmp[256];
    const int t = threadIdx.x;
    const int base = blockIdx.x * 1024 + t * 4;
    int a[4];
#pragma unroll
    for (int q = 0; q < 4; ++q) a[q] = (base + q < NN) ? cnt[base + q] : 0;
    int s = a[0] + a[1] + a[2] + a[3];
    tmp[t] = s;
    __syncthreads();
    for (int off = 1; off < 256; off <<= 1) {
        int v = 0;
        if (t >= off) v = tmp[t - off];
        __syncthreads();
        tmp[t] += v;
        __syncthreads();
    }
    int excl_s = tmp[t] - s;
    if (t == 255) bsums[blockIdx.x] = tmp[t];
    int run = excl_s;
#pragma unroll
    for (int q = 0; q < 4; ++q) {
        if (base + q < NN) excl[base + q] = run;
        run += a[q];
    }
}

__global__ __launch_bounds__(256) void scan2_kernel(int* __restrict__ bsums, int nb) {
    __shared__ int tmp[256];
    const int t = threadIdx.x;
    int s = (t < nb) ? bsums[t] : 0;
    tmp[t] = s;
    __syncthreads();
    for (int off = 1; off < 256; off <<= 1) {
        int v = 0;
        if (t >= off) v = tmp[t - off];
        __syncthreads();
        tmp[t] += v;
        __syncthreads();
    }
    if (t < nb) bsums[t] = tmp[t] - s;   // exclusive
}

// row_start(n) == excl[n] + bsums[n >> 10]  (bsums: 392B, L1-resident)

// ---------------- merged: atomic-free CSR fill (blocks < FB) + prescale ----------------
__global__ __launch_bounds__(256) void fill_prescale_kernel(const int* __restrict__ row,
                                                            const int* __restrict__ col,
                                                            const int* __restrict__ excl,
                                                            const int* __restrict__ bsums,
                                                            const unsigned char* __restrict__ xoff_u8,
                                                            const unsigned char* __restrict__ off_u8,
                                                            int* __restrict__ srcs,
                                                            const float* __restrict__ x,
                                                            const float* __restrict__ dinv_out,
                                                            ushort* __restrict__ xb) {
    if (blockIdx.x < FB) {
        // ---- fill: one edge per thread ----
        int e = blockIdx.x * 256 + threadIdx.x;   // EE % 256 == 0
        const int cl = col[e];
        const int c = e / CH;                     // chunk id
        const int rs = excl[cl] + bsums[cl >> 10];
        srcs[rs + (int)xoff_u8[(size_t)c * NN + cl] + (int)off_u8[e]] = row[e];
    } else {
        // ---- prescale: one float4 per thread ----
        int idx = (blockIdx.x - FB) * 256 + threadIdx.x;   // NN*32 % 256 == 0
        int n = idx >> 5;
        float s = dinv_out[n];
        float4 v = ((const float4*)x)[idx];
        ushort4 o;
        o.x = f2bf(v.x * s);
        o.y = f2bf(v.y * s);
        o.z = f2bf(v.z * s);
        o.w = f2bf(v.w * s);
        ((ushort4*)xb)[idx] = o;
    }
}

// ---------------- gather: 16 lanes/node, uint4 (16B) per lane, 4-edge unroll ----------------
__global__ __launch_bounds__(256) void gather_kernel(const ushort* __restrict__ src,
                                                     const int* __restrict__ excl,
                                                     const int* __restrict__ bsums,
                                                     const int* __restrict__ srcs,
                                                     ushort* __restrict__ agg) {
    const int node = blockIdx.x * 16 + (threadIdx.x >> 4);
    const int lane = threadIdx.x & 15;
    if (node >= NN) return;
    int p = excl[node] + bsums[node >> 10];
    const int end = (node + 1 < NN) ? excl[node + 1] + bsums[(node + 1) >> 10] : EE;
    float a0 = 0.f, a1 = 0.f, a2 = 0.f, a3 = 0.f;
    float a4 = 0.f, a5 = 0.f, a6 = 0.f, a7 = 0.f;

#define ACCUM(V)                                     \
    do {                                             \
        a0 += bf2f((V).x & 0xffffu);                 \
        a1 += bf2f((V).x >> 16);                     \
        a2 += bf2f((V).y & 0xffffu);                 \
        a3 += bf2f((V).y >> 16);                     \
        a4 += bf2f((V).z & 0xffffu);                 \
        a5 += bf2f((V).z >> 16);                     \
        a6 += bf2f((V).w & 0xffffu);                 \
        a7 += bf2f((V).w >> 16);                     \
    } while (0)

    for (; p + 3 < end; p += 4) {
        int s0 = srcs[p];
        int s1 = srcs[p + 1];
        int s2 = srcs[p + 2];
        int s3 = srcs[p + 3];
        uint4 v0 = ((const uint4*)(src + (size_t)s0 * DD))[lane];
        uint4 v1 = ((const uint4*)(src + (size_t)s1 * DD))[lane];
        uint4 v2 = ((const uint4*)(src + (size_t)s2 * DD))[lane];
        uint4 v3 = ((const uint4*)(src + (size_t)s3 * DD))[lane];
        ACCUM(v0); ACCUM(v1); ACCUM(v2); ACCUM(v3);
    }
    for (; p < end; ++p) {
        int s0 = srcs[p];
        uint4 v0 = ((const uint4*)(src + (size_t)s0 * DD))[lane];
        ACCUM(v0);
    }
#undef ACCUM

    uint4 o;
    o.x = (unsigned int)f2bf(a0) | ((unsigned int)f2bf(a1) << 16);
    o.y = (unsigned int)f2bf(a2) | ((unsigned int)f2bf(a3) << 16);
    o.z = (unsigned int)f2bf(a4) | ((unsigned int)f2bf(a5) << 16);
    o.w = (unsigned int)f2bf(a6) | ((unsigned int)f2bf(a7) << 16);
    ((uint4*)(agg + (size_t)node * DD))[lane] = o;
}

// ---------------- MFMA bf16 GEMM + epilogue ----------------
// C[m, j] = sum_k agg[m,k] * wb[j,k]   (wb row-major [j][k] == B^T input)
// Block: 256 threads = 4 waves, each wave one 16-row tile x all 128 cols.
// wb (bf16) staged into LDS, rows padded to 136 (2-way conflict only).
template <bool L1>
__global__ __launch_bounds__(256) void gemm_ep(const ushort* __restrict__ agg,
                                               const ushort* __restrict__ wb,
                                               const float* __restrict__ bias,
                                               const float* __restrict__ dinv_in,
                                               const float* __restrict__ dinv_out,
                                               const float* __restrict__ x,
                                               ushort* __restrict__ hs,
                                               float* __restrict__ out) {
    __shared__ ushort Ws[128 * 136];
    {   // stage wb (already bf16) into LDS: 128B per thread = 8 x uint4
        int j = threadIdx.x >> 1;
        int k0 = (threadIdx.x & 1) * 64;
        const uint4* wp = (const uint4*)(wb + (size_t)j * DD + k0);
        uint4* dst = (uint4*)(Ws + j * 136 + k0);
#pragma unroll
        for (int q = 0; q < 8; ++q) dst[q] = wp[q];
    }
    __syncthreads();

    const int wave = threadIdx.x >> 6;
    const int lane = threadIdx.x & 63;
    const int tile = blockIdx.x * 4 + wave;
    if (tile >= NTILE) return;
    const int mi = lane & 15;
    const int quad = lane >> 4;
    const int m0 = tile * 16;

    floatx4 acc[8];
#pragma unroll
    for (int t = 0; t < 8; ++t) acc[t] = (floatx4){0.f, 0.f, 0.f, 0.f};

    const ushort* ap = agg + (size_t)(m0 + mi) * DD + quad * 8;
#pragma unroll
    for (int s = 0; s < 4; ++s) {
        short8 a = *(const short8*)(ap + s * 32);
#pragma unroll
        for (int t = 0; t < 8; ++t) {
            short8 b = *(const short8*)(Ws + (t * 16 + mi) * 136 + s * 32 + quad * 8);
            acc[t] = __builtin_amdgcn_mfma_f32_16x16x32_bf16(a, b, acc[t], 0, 0, 0);
        }
    }

    // C/D layout: col = lane&15, row = quad*4 + reg
    float dv[4], dov[4];
#pragma unroll
    for (int i = 0; i < 4; ++i) {
        int r = m0 + quad * 4 + i;
        dv[i] = dinv_in[r];
        if (L1) dov[i] = dinv_out[r];
    }
#pragma unroll
    for (int t = 0; t < 8; ++t) {
        int c = t * 16 + mi;
        float bv = bias[c];
#pragma unroll
        for (int i = 0; i < 4; ++i) {
            int r = m0 + quad * 4 + i;
            float o = (acc[t][i] + bv) * dv[i];
            if (L1) {
                o += x[(size_t)r * DD + c];
                o = fmaxf(o, 0.f);
                hs[(size_t)r * DD + c] = f2bf(o * dov[i]);
            } else {
                out[(size_t)r * DD + c] = o;
            }
        }
    }
}

extern "C" void kernel_launch(void* const* d_in, const int* in_sizes, int n_in,
                              void* d_out, int out_size, void* d_ws, size_t ws_size,
                              hipStream_t stream) {
    const float* x  = (const float*)d_in[0];
    const int*   ei = (const int*)d_in[1];
    const float* W1 = (const float*)d_in[2];
    const float* b1 = (const float*)d_in[3];
    const float* W2 = (const float*)d_in[4];
    const float* b2 = (const float*)d_in[5];
    float* out = (float*)d_out;

    const int* row = ei;        // edge_index[0] (source)
    const int* col = ei + EE;   // edge_index[1] (target)

    // workspace layout. The agg region (25.6MB) hosts the CSR-build
    // temporaries (off_u8 0.8MB, partial_in/out 6.4MB each, xoff 6.4MB),
    // all dead before the first gather writes agg. No memset anywhere.
    ushort* agg     = (ushort*)d_ws;                 // N*DD bf16 (25.6 MB)
    ushort* xb      = agg + (size_t)NN * DD;         // N*DD bf16 (25.6 MB) -> becomes hs
    float* dinv_out = (float*)(xb + (size_t)NN * DD);
    float* dinv_in  = dinv_out + NN;
    int*   cnt      = (int*)(dinv_in + NN);          // N (cnt_total for scan)
    int*   excl     = cnt + NN;                      // N
    int*   srcs     = excl + NN;                     // E
    int*   bsums    = srcs + EE;                     // 256
    ushort* wb1     = (ushort*)(bsums + 256);        // 128*128 bf16 (32 KB)
    ushort* wb2     = wb1 + DD * DD;                 // 128*128 bf16 (32 KB)

    unsigned char* off_u8      = (unsigned char*)agg;              // E bytes (aliased)
    unsigned int*  partial_in  = (unsigned int*)(off_u8 + EE);     // CC*NWORDS (aliased)
    unsigned int*  partial_out = partial_in + CC * NWORDS;         // CC*NWORDS (aliased)
    unsigned int*  xoff        = partial_out + CC * NWORDS;        // CC*NWORDS (aliased)

    // ---- CSR build (+ embedded wconv), 4 launches ----
    count_kernel<<<256, 512, 0, stream>>>(row, col, partial_out, partial_in, off_u8,
                                          W1, W2, wb1, wb2);
    node_kernel<<<(NWORDS + 255) / 256, 256, 0, stream>>>(partial_out, partial_in, cnt, xoff,
                                                          dinv_out, dinv_in);
    scan1_kernel<<<NB1, 256, 0, stream>>>(cnt, excl, bsums);
    scan2_kernel<<<1, 256, 0, stream>>>(bsums, NB1);

    // ---- fill + prescale (merged, 1 launch) ----
    fill_prescale_kernel<<<FB + PB, 256, 0, stream>>>(row, col, excl, bsums,
                                                      (const unsigned char*)xoff, off_u8, srcs,
                                                      x, dinv_out, xb);

    // ---- layer 1 ----
    gather_kernel<<<(NN + 15) / 16, 256, 0, stream>>>(xb, excl, bsums, srcs, agg);
    gemm_ep<true><<<(NTILE + 3) / 4, 256, 0, stream>>>(agg, wb1, b1, dinv_in, dinv_out, x,
                                                       /*hs=*/xb, /*out=*/nullptr);

    // ---- layer 2 ----
    gather_kernel<<<(NN + 15) / 16, 256, 0, stream>>>(xb, excl, bsums, srcs, agg);
    gemm_ep<false><<<(NTILE + 3) / 4, 256, 0, stream>>>(agg, wb2, b2, dinv_in, nullptr, nullptr,
                                                        nullptr, out);
}